// Round 16
// baseline (933.599 us; speedup 1.0000x reference)
//
#include <hip/hip_runtime.h>

typedef __attribute__((ext_vector_type(8))) short short8;
typedef __attribute__((ext_vector_type(4))) float f32x4;
typedef __attribute__((ext_vector_type(4))) unsigned short u16x4;
typedef __attribute__((ext_vector_type(8))) unsigned short u16x8;

#define BDIM 8
#define CDIM 768
#define C3 2304
#define C4 3072
#define HEADS 12
#define HD 64
#define HWD 4096
#define TOKS 32768

__device__ __forceinline__ float bf2f(unsigned short u) {
    union { unsigned int i; float f; } x; x.i = ((unsigned int)u) << 16; return x.f;
}
__device__ __forceinline__ unsigned short f2bf(float f) {
    union { float f; unsigned int i; } x; x.f = f;
    unsigned int r = x.i + 0x7FFFu + ((x.i >> 16) & 1u);
    return (unsigned short)(r >> 16);
}

// async global->LDS, 16B per lane; offset-0 form only (nonzero imm offset broke on gfx950, R6)
__device__ __forceinline__ void gload_lds16(const unsigned short* g, unsigned short* l) {
    __builtin_amdgcn_global_load_lds(
        (const __attribute__((address_space(1))) void*)g,
        (__attribute__((address_space(3))) void*)l, 16, 0, 0);
}

// ---------------- weight prep ----------------
__global__ __launch_bounds__(256) void convert_f32_bf16(
    const float* __restrict__ src, unsigned short* __restrict__ dst, int n)
{
    int i = (blockIdx.x * 256 + threadIdx.x) * 4;
    if (i + 3 >= n + 4) return;
    if (i + 3 < n) {
        float4 v = *(const float4*)&src[i];
        dst[i + 0] = f2bf(v.x); dst[i + 1] = f2bf(v.y);
        dst[i + 2] = f2bf(v.z); dst[i + 3] = f2bf(v.w);
    }
}

// src [R][Cc] f32 -> dst [Cc][R] bf16
__global__ __launch_bounds__(256) void transpose_w(
    const float* __restrict__ src, unsigned short* __restrict__ dst, int R, int Cc)
{
    const int n0 = blockIdx.x * 64, k0 = blockIdx.y * 64;
    __shared__ float t[64][65];
    #pragma unroll
    for (int s = 0; s < 16; ++s) {
        int flat = threadIdx.x + 256 * s;
        int i = flat >> 6, j = flat & 63;
        t[i][j] = src[(long)(k0 + i) * Cc + n0 + j];
    }
    __syncthreads();
    #pragma unroll
    for (int s = 0; s < 16; ++s) {
        int flat = threadIdx.x + 256 * s;
        int jn = flat >> 6, ik = flat & 63;
        dst[(long)(n0 + jn) * R + k0 + ik] = f2bf(t[ik][jn]);
    }
}

// ---------------- spatial rms-norm stats (ddof=1): sout = w/(std+eps) ----------------
__global__ __launch_bounds__(256) void stats_spatial_f32(
    const float* __restrict__ x, const float* __restrict__ wgt,
    float* __restrict__ sout, float eps)
{
    const int bc = blockIdx.x;
    const int c = bc % CDIM;
    const float4* p4 = (const float4*)(x + (long)bc * HWD);
    float s = 0.f, ss = 0.f;
    #pragma unroll
    for (int k = 0; k < 4; ++k) {
        float4 v = p4[threadIdx.x + 256 * k];
        s  += v.x + v.y + v.z + v.w;
        ss += v.x * v.x + v.y * v.y + v.z * v.z + v.w * v.w;
    }
    #pragma unroll
    for (int m = 1; m < 64; m <<= 1) { s += __shfl_xor(s, m); ss += __shfl_xor(ss, m); }
    __shared__ float rs[4], rss[4];
    int w = threadIdx.x >> 6, lane = threadIdx.x & 63;
    if (lane == 0) { rs[w] = s; rss[w] = ss; }
    __syncthreads();
    if (threadIdx.x == 0) {
        float S = rs[0] + rs[1] + rs[2] + rs[3];
        float Q = rss[0] + rss[1] + rss[2] + rss[3];
        float var = (Q - S * S * (1.f / 4096.f)) * (1.f / 4095.f);
        sout[bc] = wgt[c] / (sqrtf(var) + eps);
    }
}

// stats over spatial for BHWC bf16 tensor; grid = 8*12 blocks (b, 64-ch group)
__global__ __launch_bounds__(256) void stats_spatial_bf16(
    const unsigned short* __restrict__ t, const float* __restrict__ wgt,
    float* __restrict__ sout, float eps)
{
    const int b = blockIdx.x / 12, cg = blockIdx.x % 12;
    const int sub = threadIdx.x & 15, tr = threadIdx.x >> 4;
    const unsigned short* base = t + (long)b * HWD * CDIM + cg * 64 + sub * 4;
    float s[4] = {0.f, 0.f, 0.f, 0.f}, q[4] = {0.f, 0.f, 0.f, 0.f};
    for (int i = 0; i < 256; ++i) {
        const int token = tr + 16 * i;
        u16x4 v = *(const u16x4*)(base + (long)token * CDIM);
        #pragma unroll
        for (int j = 0; j < 4; ++j) { float f = bf2f(v[j]); s[j] += f; q[j] += f * f; }
    }
    __shared__ float ssum[16][64], ssq[16][64];
    #pragma unroll
    for (int j = 0; j < 4; ++j) { ssum[tr][sub * 4 + j] = s[j]; ssq[tr][sub * 4 + j] = q[j]; }
    __syncthreads();
    if (threadIdx.x < 64) {
        const int c = threadIdx.x;
        float S = 0.f, Q = 0.f;
        #pragma unroll
        for (int r = 0; r < 16; ++r) { S += ssum[r][c]; Q += ssq[r][c]; }
        const float var = (Q - S * S * (1.f / 4096.f)) * (1.f / 4095.f);
        const int cglob = cg * 64 + c;
        sout[b * CDIM + cglob] = wgt[cglob] / (sqrtf(var) + eps);
    }
}

// ---------------- h = x * s1, BCHW f32 -> BHWC bf16 ----------------
__global__ __launch_bounds__(256) void make_h(
    const float* __restrict__ x, const float* __restrict__ s1,
    unsigned short* __restrict__ h)
{
    const int hw0 = blockIdx.x * 64, c0 = blockIdx.y * 64, b = blockIdx.z;
    __shared__ float t[64][65];
    #pragma unroll
    for (int s = 0; s < 16; ++s) {
        int flat = threadIdx.x + 256 * s;
        int ci = flat >> 6, hj = flat & 63;
        t[ci][hj] = x[(long)(b * CDIM + c0 + ci) * HWD + hw0 + hj];
    }
    __syncthreads();
    #pragma unroll
    for (int s = 0; s < 16; ++s) {
        int flat = threadIdx.x + 256 * s;
        int hi = flat >> 6, cj = flat & 63;
        float v = t[cj][hi] * s1[b * CDIM + c0 + cj];
        h[(long)(b * HWD + hw0 + hi) * CDIM + c0 + cj] = f2bf(v);
    }
}

// ---------------- GEMM 256x128 tile, BK_sub=32, 3-slot ring, single-barrier, 2 blocks/CU ----------------
// out[M][N] = A[M][K] * BT[N][K]^T (+bias)(+gelu), bf16 in/out.
// 512 threads = 8 waves (4m x 2n), per-wave 64x64 (acc 64 AGPR) -> 2 blocks/CU (LDS 72KB).
// R16 schedule = R7's one-barrier-per-subtile + R12's cross-block overlap:
// body j reads slot j%3, stages sub j+2 into slot (j+2)%3 (= slot read in body j-1,
// drained by the previous end barrier -> NO read-drain barrier needed), MFMA with
// compiler-interleaved lgkmcnt, then counted vmcnt + one barrier.
// LDS: A [3][256][32] elems at [0,24576), B [3][128][32] at +24576. Granule swizzle:
// 16B granule (row,pos) holds k-chunk pos ^ ((row>>1)&3); conflict-free ds_read_b128.
template<int GELU>
__global__ __launch_bounds__(512, 4) void gemm256(
    const unsigned short* __restrict__ A, const unsigned short* __restrict__ BT,
    const float* __restrict__ bias, unsigned short* __restrict__ out,
    int M, int N, int K)
{
    extern __shared__ unsigned short smem[];
    const int tid = threadIdx.x;
    const int lane = tid & 63, w = tid >> 6;
    const int wm = w >> 1, wn = w & 1;            // 4 x 2 waves
    const int lr = lane & 15, g = lane >> 4;

    // T1: XCD-contiguous logical id, n fastest (A-panel shared in XCD L2)
    const int nwg = gridDim.x;
    const int logical = (blockIdx.x & 7) * (nwg >> 3) + (blockIdx.x >> 3);
    const int gnx = N >> 7;
    const int n0 = (logical % gnx) << 7;
    const int m0 = (logical / gnx) << 8;

    const int ka = (((tid & 3) ^ ((tid >> 3) & 3)) << 3);
    const unsigned short* aS0 = A + (long)(m0 + (tid >> 2)) * K + ka;
    const unsigned short* aS1 = A + (long)(m0 + 128 + (tid >> 2)) * K + ka;
    const unsigned short* bS = BT + (long)(n0 + (tid >> 2)) * K + ka;
    unsigned short* dA0 = smem + (tid & ~63) * 8;
    unsigned short* dA1 = dA0 + 4096;
    unsigned short* dB  = smem + 24576 + (tid & ~63) * 8;

#define GSTAGE(S) do { \
        gload_lds16(aS0, dA0 + (S) * 8192); \
        gload_lds16(aS1, dA1 + (S) * 8192); \
        gload_lds16(bS,  dB  + (S) * 4096); \
        aS0 += 32; aS1 += 32; bS += 32; } while (0)

    const int nsub = K >> 5;                         // 24 or 96 (divisible by 3)
    const int koff = ((g ^ ((lr >> 1) & 3)) << 3);
    const unsigned short* baseA = smem + (wm * 64 + lr) * 32 + koff;
    const unsigned short* baseB = smem + 24576 + (wn * 64 + lr) * 32 + koff;

    f32x4 acc[4][4] = {};

    GSTAGE(0); GSTAGE(1);                             // subs 0,1 in flight (6 loads)
    asm volatile("s_waitcnt vmcnt(3)" ::: "memory");  // sub0 landed
    __builtin_amdgcn_s_barrier();

// body: read slot U, stage (into slot (U+2)%3, drained in body U-1), MFMA
// (compiler inserts fine lgkmcnt before dependent MFMAs), counted vmcnt, barrier.
#define SUBTILE(U, STG, WAITN) do { \
        short8 bf[4], af[4]; \
        _Pragma("unroll") \
        for (int ni = 0; ni < 4; ++ni) bf[ni] = *(const short8*)(baseB + (U) * 4096 + ni * 512); \
        _Pragma("unroll") \
        for (int mi = 0; mi < 4; ++mi) af[mi] = *(const short8*)(baseA + (U) * 8192 + mi * 512); \
        STG; \
        __builtin_amdgcn_s_setprio(1); \
        _Pragma("unroll") \
        for (int mi = 0; mi < 4; ++mi) \
            _Pragma("unroll") \
            for (int ni = 0; ni < 4; ++ni) \
                acc[mi][ni] = __builtin_amdgcn_mfma_f32_16x16x32_bf16(af[mi], bf[ni], acc[mi][ni], 0, 0, 0); \
        __builtin_amdgcn_s_setprio(0); \
        asm volatile("s_waitcnt vmcnt(" #WAITN ")" ::: "memory"); \
        __builtin_amdgcn_s_barrier(); \
        __builtin_amdgcn_sched_barrier(0); } while (0)

    // main triples: bodies 0..nsub-4 all stage (targets sub j+2 <= nsub-2)
    for (int j3 = 0; j3 + 3 < nsub; j3 += 3) {
        SUBTILE(0, GSTAGE(2), 3);
        SUBTILE(1, GSTAGE(0), 3);
        SUBTILE(2, GSTAGE(1), 3);
    }
    // tail triple (bodies nsub-3..nsub-1): body nsub-3 stages sub nsub-1; then drain
    SUBTILE(0, GSTAGE(2), 3);
    SUBTILE(1, , 0);
    SUBTILE(2, , 0);
#undef SUBTILE
#undef GSTAGE

    #pragma unroll
    for (int mi = 0; mi < 4; ++mi) {
        #pragma unroll
        for (int ni = 0; ni < 4; ++ni) {
            const int gcol = n0 + wn * 64 + ni * 16 + lr;
            const float bv = bias[gcol];
            #pragma unroll
            for (int r = 0; r < 4; ++r) {
                const int grow = m0 + wm * 64 + mi * 16 + g * 4 + r;
                float v = acc[mi][ni][r] + bv;
                if (GELU) v = 0.5f * v * (1.f + erff(v * 0.70710678118f));
                out[(long)grow * N + gcol] = f2bf(v);
            }
        }
    }
}

// ---------------- per-head q/k LayerNorm (ddof=0, eps 1e-5) in place ----------------
__global__ __launch_bounds__(256) void qk_layernorm(
    unsigned short* __restrict__ qkv,
    const float* __restrict__ qw, const float* __restrict__ qb,
    const float* __restrict__ kw, const float* __restrict__ kb)
{
    const int pairIdx = blockIdx.x * 16 + (threadIdx.x >> 4);
    const int token = pairIdx / HEADS, he = pairIdx % HEADS;
    const int c4 = (threadIdx.x & 15) * 4;
    const long base = (long)token * C3 + he * 192;
    #pragma unroll
    for (int which = 0; which < 2; ++which) {
        const long off = base + which * 64 + c4;
        u16x4 v = *(u16x4*)&qkv[off];
        float f[4];
        #pragma unroll
        for (int j = 0; j < 4; ++j) f[j] = bf2f(v[j]);
        float s = f[0] + f[1] + f[2] + f[3];
        float q = f[0] * f[0] + f[1] * f[1] + f[2] * f[2] + f[3] * f[3];
        #pragma unroll
        for (int m = 1; m < 16; m <<= 1) { s += __shfl_xor(s, m); q += __shfl_xor(q, m); }
        const float mean = s * (1.f / 64.f);
        const float var = q * (1.f / 64.f) - mean * mean;
        const float rstd = rsqrtf(var + 1e-5f);
        const float* W = which ? kw : qw;
        const float* Bv = which ? kb : qb;
        u16x4 o;
        #pragma unroll
        for (int j = 0; j < 4; ++j)
            o[j] = f2bf((f[j] - mean) * rstd * W[c4 + j] + Bv[c4 + j]);
        *(u16x4*)&qkv[off] = o;
    }
}

// ---------------- axial attention: one wave per (b,head,line); AXIS 0=row(attend W), 1=col(attend H) ----------------
template<int AXIS>
__global__ __launch_bounds__(128) void attn_axial(
    const unsigned short* __restrict__ qkv, unsigned short* __restrict__ a)
{
    __shared__ unsigned short lds[2][2][64 * 72];
    const int tid = threadIdx.x;
    const int lane = tid & 63, w = tid >> 6;
    const int lineG = blockIdx.x * 2 + w;
    const int b = lineG / 768;
    const int rem = lineG - b * 768;
    const int he = rem >> 6, line = rem & 63;
    const int ts = (AXIS == 0) ? 1 : 64;
    const long token0 = (long)b * HWD + (AXIS == 0 ? line * 64 : line);
    const long qbase = token0 * C3 + he * 192;
    unsigned short* VT = &lds[w][0][0];
    unsigned short* P  = &lds[w][1][0];
    const int lr = lane & 15, g = lane >> 4;

    // stage V transposed: VT[d][key], rows padded to 72
    {
        const int keyr = lane >> 3, d8 = (lane & 7) << 3;
        #pragma unroll
        for (int it = 0; it < 8; ++it) {
            const int key = it * 8 + keyr;
            u16x8 v = *(const u16x8*)&qkv[qbase + (long)key * ts * C3 + 128 + d8];
            #pragma unroll
            for (int j = 0; j < 8; ++j) VT[(d8 + j) * 72 + key] = v[j];
        }
    }

    // Q,K fragments straight from global
    short8 qf[4][2], kf[4][2];
    #pragma unroll
    for (int i = 0; i < 4; ++i)
        #pragma unroll
        for (int kk = 0; kk < 2; ++kk) {
            const long rb = qbase + (long)(i * 16 + lr) * ts * C3 + kk * 32 + g * 8;
            qf[i][kk] = *(const short8*)&qkv[rb];
            kf[i][kk] = *(const short8*)&qkv[rb + 64];
        }

    f32x4 acc[4][4] = {};
    #pragma unroll
    for (int mi = 0; mi < 4; ++mi)
        #pragma unroll
        for (int ni = 0; ni < 4; ++ni) {
            acc[mi][ni] = __builtin_amdgcn_mfma_f32_16x16x32_bf16(qf[mi][0], kf[ni][0], acc[mi][ni], 0, 0, 0);
            acc[mi][ni] = __builtin_amdgcn_mfma_f32_16x16x32_bf16(qf[mi][1], kf[ni][1], acc[mi][ni], 0, 0, 0);
        }

    // softmax per row (scale 1/8); D layout: row = mi*16+4g+r, col = ni*16+lr
    #pragma unroll
    for (int mi = 0; mi < 4; ++mi)
        #pragma unroll
        for (int r = 0; r < 4; ++r) {
            float mx = -1e30f;
            #pragma unroll
            for (int ni = 0; ni < 4; ++ni) {
                float v = acc[mi][ni][r] * 0.125f; acc[mi][ni][r] = v; mx = fmaxf(mx, v);
            }
            #pragma unroll
            for (int m = 1; m < 16; m <<= 1) mx = fmaxf(mx, __shfl_xor(mx, m));
            float s = 0.f;
            #pragma unroll
            for (int ni = 0; ni < 4; ++ni) {
                float e = __expf(acc[mi][ni][r] - mx); acc[mi][ni][r] = e; s += e;
            }
            #pragma unroll
            for (int m = 1; m < 16; m <<= 1) s += __shfl_xor(s, m);
            const float inv = 1.f / s;
            const int row = mi * 16 + 4 * g + r;
            #pragma unroll
            for (int ni = 0; ni < 4; ++ni)
                P[row * 72 + ni * 16 + lr] = f2bf(acc[mi][ni][r] * inv);
        }
    __syncthreads();

    // PV
    short8 pa[4][2], vb[4][2];
    #pragma unroll
    for (int i = 0; i < 4; ++i)
        #pragma unroll
        for (int kk = 0; kk < 2; ++kk) {
            pa[i][kk] = *(const short8*)&P[(i * 16 + lr) * 72 + kk * 32 + g * 8];
            vb[i][kk] = *(const short8*)&VT[(i * 16 + lr) * 72 + kk * 32 + g * 8];
        }
    f32x4 o2[4][4] = {};
    #pragma unroll
    for (int mi = 0; mi < 4; ++mi)
        #pragma unroll
        for (int ni = 0; ni < 4; ++ni) {
            o2[mi][ni] = __builtin_amdgcn_mfma_f32_16x16x32_bf16(pa[mi][0], vb[ni][0], o2[mi][ni], 0, 0, 0);
            o2[mi][ni] = __builtin_amdgcn_mfma_f32_16x16x32_bf16(pa[mi][1], vb[ni][1], o2[mi][ni], 0, 0, 0);
        }

    // write 0.5*result; col pass accumulates onto row pass
    #pragma unroll
    for (int mi = 0; mi < 4; ++mi)
        #pragma unroll
        for (int r = 0; r < 4; ++r) {
            const int q = mi * 16 + 4 * g + r;
            const long tok = token0 + (long)q * ts;
            #pragma unroll
            for (int ni = 0; ni < 4; ++ni) {
                const int d = ni * 16 + lr;
                const long addr = tok * CDIM + he * 64 + d;
                const float v = o2[mi][ni][r] * 0.5f;
                if (AXIS == 0) a[addr] = f2bf(v);
                else           a[addr] = f2bf(bf2f(a[addr]) + v);
            }
        }
}

// ---------------- a *= s2[b][c] in place (bf16 BHWC) ----------------
__global__ __launch_bounds__(256) void scale_inplace(
    unsigned short* __restrict__ a, const float* __restrict__ s2)
{
    const long i = ((long)blockIdx.x * 256 + threadIdx.x) * 4;
    const int c = (int)(i % CDIM);
    const int b = (int)(i / ((long)CDIM * HWD));
    u16x4 v = *(u16x4*)&a[i];
    u16x4 o;
    #pragma unroll
    for (int j = 0; j < 4; ++j) o[j] = f2bf(bf2f(v[j]) * s2[b * CDIM + c + j]);
    *(u16x4*)&a[i] = o;
}

// ---------------- x1b = bf16(x + gamma_att*o), BHWC (no dout write) ----------------
__global__ __launch_bounds__(256) void x1_combine(
    const unsigned short* __restrict__ o, const float* __restrict__ x,
    const float* __restrict__ gamma, unsigned short* __restrict__ x1b)
{
    const int hw0 = blockIdx.x * 64, c0 = blockIdx.y * 64, b = blockIdx.z;
    __shared__ float t[64][65];
    #pragma unroll
    for (int s = 0; s < 16; ++s) {
        int flat = threadIdx.x + 256 * s;
        int i = flat >> 6, j = flat & 63;
        t[i][j] = bf2f(o[(long)(b * HWD + hw0 + i) * CDIM + c0 + j]);
    }
    __syncthreads();
    #pragma unroll
    for (int s = 0; s < 16; ++s) {
        int flat = threadIdx.x + 256 * s;
        int j = flat >> 6, i = flat & 63;
        const long xi = (long)(b * CDIM + c0 + j) * HWD + hw0 + i;
        t[i][j] = x[xi] + gamma[c0 + j] * t[i][j];
    }
    __syncthreads();
    #pragma unroll
    for (int s = 0; s < 16; ++s) {
        int flat = threadIdx.x + 256 * s;
        int i = flat >> 6, j = flat & 63;
        x1b[(long)(b * HWD + hw0 + i) * CDIM + c0 + j] = f2bf(t[i][j]);
    }
}

// ---------------- dout(BCHW f32) = x1b + gamma_mlp*s3*m  (single write) ----------------
__global__ __launch_bounds__(256) void final_combine(
    const unsigned short* __restrict__ x1b, const unsigned short* __restrict__ m,
    const float* __restrict__ gm, const float* __restrict__ s3,
    float* __restrict__ dout)
{
    const int hw0 = blockIdx.x * 64, c0 = blockIdx.y * 64, b = blockIdx.z;
    __shared__ float t[64][65];
    #pragma unroll
    for (int s = 0; s < 16; ++s) {
        int flat = threadIdx.x + 256 * s;
        int i = flat >> 6, j = flat & 63;
        const long tok = (long)(b * HWD + hw0 + i) * CDIM + c0 + j;
        t[i][j] = bf2f(x1b[tok]) + gm[c0 + j] * s3[b * CDIM + c0 + j] * bf2f(m[tok]);
    }
    __syncthreads();
    #pragma unroll
    for (int s = 0; s < 16; ++s) {
        int flat = threadIdx.x + 256 * s;
        int j = flat >> 6, i = flat & 63;
        dout[(long)(b * CDIM + c0 + j) * HWD + hw0 + i] = t[i][j];
    }
}

extern "C" void kernel_launch(void* const* d_in, const int* in_sizes, int n_in,
                              void* d_out, int out_size, void* d_ws, size_t ws_size,
                              hipStream_t stream) {
    const float* x      = (const float*)d_in[0];
    const float* n1w    = (const float*)d_in[2];
    const float* n2w    = (const float*)d_in[3];
    const float* mlw    = (const float*)d_in[4];
    const float* Win    = (const float*)d_in[5];
    const float* bin    = (const float*)d_in[6];
    const float* Wout   = (const float*)d_in[7];
    const float* bout   = (const float*)d_in[8];
    const float* qn_w   = (const float*)d_in[9];
    const float* qn_b   = (const float*)d_in[10];
    const float* kn_w   = (const float*)d_in[11];
    const float* kn_b   = (const float*)d_in[12];
    const float* gatt   = (const float*)d_in[13];
    const float* gmlp   = (const float*)d_in[14];
    const float* W1     = (const float*)d_in[15];
    const float* b1     = (const float*)d_in[16];
    const float* W2     = (const float*)d_in[17];
    const float* b2     = (const float*)d_in[18];
    float* dout = (float*)d_out;
    char* ws = (char*)d_ws;

    unsigned short* wQ  = (unsigned short*)(ws);                  // Win  bf16 [2304][768]
    unsigned short* wO  = (unsigned short*)(ws + (4L << 20));     // Wout bf16 [768][768]
    unsigned short* w1t = (unsigned short*)(ws + (6L << 20));     // W1^T bf16 [3072][768]
    unsigned short* w2t = (unsigned short*)(ws + (11L << 20));    // W2^T bf16 [768][3072]
    float* s1 = (float*)(ws + (16L << 20));
    float* s2 = s1 + 6144;
    float* s3 = s2 + 6144;
    unsigned short* bufH = (unsigned short*)(ws + (17L << 20));   // 48MB: h -> o -> m
    unsigned short* bufQ = (unsigned short*)(ws + (65L << 20));   // 144MB: qkv -> hidden
    unsigned short* bufA = (unsigned short*)(ws + (209L << 20));  // 48MB: a -> x1b (bhwc)

    // allow 72KB dynamic LDS for the GEMM (2 blocks/CU within the 160KB/CU budget)
    hipFuncSetAttribute((const void*)&gemm256<0>, hipFuncAttributeMaxDynamicSharedMemorySize, 73728);
    hipFuncSetAttribute((const void*)&gemm256<1>, hipFuncAttributeMaxDynamicSharedMemorySize, 73728);

    // weight prep
    convert_f32_bf16<<<1728, 256, 0, stream>>>(Win, wQ, C3 * CDIM);
    convert_f32_bf16<<<576, 256, 0, stream>>>(Wout, wO, CDIM * CDIM);
    transpose_w<<<dim3(C4 / 64, CDIM / 64), 256, 0, stream>>>(W1, w1t, CDIM, C4);
    transpose_w<<<dim3(CDIM / 64, C4 / 64), 256, 0, stream>>>(W2, w2t, C4, CDIM);

    // norm1 + h
    stats_spatial_f32<<<BDIM * CDIM, 256, 0, stream>>>(x, n1w, s1, 1e-6f);
    make_h<<<dim3(64, 12, 8), 256, 0, stream>>>(x, s1, bufH);

    // qkv = h @ Win^T + bin   (grid 128*18 = 2304 blocks)
    gemm256<0><<<(TOKS / 256) * (C3 / 128), 512, 73728, stream>>>(bufH, wQ, bin, bufQ, TOKS, C3, CDIM);
    qk_layernorm<<<TOKS * HEADS / 16, 256, 0, stream>>>(bufQ, qn_w, qn_b, kn_w, kn_b);

    // axial attention, a = 0.5*(xx + xy)
    attn_axial<0><<<BDIM * HEADS * 64 / 2, 128, 0, stream>>>(bufQ, bufA);
    attn_axial<1><<<BDIM * HEADS * 64 / 2, 128, 0, stream>>>(bufQ, bufA);

    // norm2 + Wout + residual   (grid 128*6 = 768)
    stats_spatial_bf16<<<BDIM * 12, 256, 0, stream>>>(bufA, n2w, s2, 1e-6f);
    scale_inplace<<<TOKS * CDIM / 1024, 256, 0, stream>>>(bufA, s2);
    gemm256<0><<<(TOKS / 256) * (CDIM / 128), 512, 73728, stream>>>(bufA, wO, bout, bufH, TOKS, CDIM, CDIM);
    x1_combine<<<dim3(64, 12, 8), 256, 0, stream>>>(bufH, x, gatt, bufA);

    // MLP in 2 token chunks (hidden reuses bufQ; m overwrites o in bufH)
    for (int ch = 0; ch < 2; ++ch) {
        const unsigned short* x1c = bufA + (long)ch * 16384 * CDIM;
        unsigned short* mc = bufH + (long)ch * 16384 * CDIM;
        gemm256<1><<<(16384 / 256) * (C4 / 128), 512, 73728, stream>>>(x1c, w1t, b1, bufQ, 16384, C4, CDIM);
        gemm256<0><<<(16384 / 256) * (CDIM / 128), 512, 73728, stream>>>(bufQ, w2t, b2, mc, 16384, CDIM, C4);
    }

    // mlp norm + single-pass final output
    stats_spatial_bf16<<<BDIM * 12, 256, 0, stream>>>(bufH, mlw, s3, 1e-6f);
    final_combine<<<dim3(64, 12, 8), 256, 0, stream>>>(bufA, bufH, gmlp, s3, dout);
}

// Round 17
// 923.161 us; speedup vs baseline: 1.0113x; 1.0113x over previous
//
#include <hip/hip_runtime.h>

typedef __attribute__((ext_vector_type(8))) short short8;
typedef __attribute__((ext_vector_type(4))) float f32x4;
typedef __attribute__((ext_vector_type(4))) unsigned short u16x4;
typedef __attribute__((ext_vector_type(8))) unsigned short u16x8;

#define BDIM 8
#define CDIM 768
#define C3 2304
#define C4 3072
#define HEADS 12
#define HD 64
#define HWD 4096
#define TOKS 32768

__device__ __forceinline__ float bf2f(unsigned short u) {
    union { unsigned int i; float f; } x; x.i = ((unsigned int)u) << 16; return x.f;
}
__device__ __forceinline__ unsigned short f2bf(float f) {
    union { float f; unsigned int i; } x; x.f = f;
    unsigned int r = x.i + 0x7FFFu + ((x.i >> 16) & 1u);
    return (unsigned short)(r >> 16);
}

// async global->LDS, 16B per lane; offset-0 form only (nonzero imm offset broke on gfx950, R6)
__device__ __forceinline__ void gload_lds16(const unsigned short* g, unsigned short* l) {
    __builtin_amdgcn_global_load_lds(
        (const __attribute__((address_space(1))) void*)g,
        (__attribute__((address_space(3))) void*)l, 16, 0, 0);
}

// ---------------- weight prep ----------------
__global__ __launch_bounds__(256) void convert_f32_bf16(
    const float* __restrict__ src, unsigned short* __restrict__ dst, int n)
{
    int i = (blockIdx.x * 256 + threadIdx.x) * 4;
    if (i + 3 >= n + 4) return;
    if (i + 3 < n) {
        float4 v = *(const float4*)&src[i];
        dst[i + 0] = f2bf(v.x); dst[i + 1] = f2bf(v.y);
        dst[i + 2] = f2bf(v.z); dst[i + 3] = f2bf(v.w);
    }
}

// src [R][Cc] f32 -> dst [Cc][R] bf16
__global__ __launch_bounds__(256) void transpose_w(
    const float* __restrict__ src, unsigned short* __restrict__ dst, int R, int Cc)
{
    const int n0 = blockIdx.x * 64, k0 = blockIdx.y * 64;
    __shared__ float t[64][65];
    #pragma unroll
    for (int s = 0; s < 16; ++s) {
        int flat = threadIdx.x + 256 * s;
        int i = flat >> 6, j = flat & 63;
        t[i][j] = src[(long)(k0 + i) * Cc + n0 + j];
    }
    __syncthreads();
    #pragma unroll
    for (int s = 0; s < 16; ++s) {
        int flat = threadIdx.x + 256 * s;
        int jn = flat >> 6, ik = flat & 63;
        dst[(long)(n0 + jn) * R + k0 + ik] = f2bf(t[ik][jn]);
    }
}

// ---------------- spatial rms-norm stats (ddof=1): sout = w/(std+eps) ----------------
__global__ __launch_bounds__(256) void stats_spatial_f32(
    const float* __restrict__ x, const float* __restrict__ wgt,
    float* __restrict__ sout, float eps)
{
    const int bc = blockIdx.x;
    const int c = bc % CDIM;
    const float4* p4 = (const float4*)(x + (long)bc * HWD);
    float s = 0.f, ss = 0.f;
    #pragma unroll
    for (int k = 0; k < 4; ++k) {
        float4 v = p4[threadIdx.x + 256 * k];
        s  += v.x + v.y + v.z + v.w;
        ss += v.x * v.x + v.y * v.y + v.z * v.z + v.w * v.w;
    }
    #pragma unroll
    for (int m = 1; m < 64; m <<= 1) { s += __shfl_xor(s, m); ss += __shfl_xor(ss, m); }
    __shared__ float rs[4], rss[4];
    int w = threadIdx.x >> 6, lane = threadIdx.x & 63;
    if (lane == 0) { rs[w] = s; rss[w] = ss; }
    __syncthreads();
    if (threadIdx.x == 0) {
        float S = rs[0] + rs[1] + rs[2] + rs[3];
        float Q = rss[0] + rss[1] + rss[2] + rss[3];
        float var = (Q - S * S * (1.f / 4096.f)) * (1.f / 4095.f);
        sout[bc] = wgt[c] / (sqrtf(var) + eps);
    }
}

// stats over spatial for BHWC bf16 tensor; grid = 8*12 blocks (b, 64-ch group)
__global__ __launch_bounds__(256) void stats_spatial_bf16(
    const unsigned short* __restrict__ t, const float* __restrict__ wgt,
    float* __restrict__ sout, float eps)
{
    const int b = blockIdx.x / 12, cg = blockIdx.x % 12;
    const int sub = threadIdx.x & 15, tr = threadIdx.x >> 4;
    const unsigned short* base = t + (long)b * HWD * CDIM + cg * 64 + sub * 4;
    float s[4] = {0.f, 0.f, 0.f, 0.f}, q[4] = {0.f, 0.f, 0.f, 0.f};
    for (int i = 0; i < 256; ++i) {
        const int token = tr + 16 * i;
        u16x4 v = *(const u16x4*)(base + (long)token * CDIM);
        #pragma unroll
        for (int j = 0; j < 4; ++j) { float f = bf2f(v[j]); s[j] += f; q[j] += f * f; }
    }
    __shared__ float ssum[16][64], ssq[16][64];
    #pragma unroll
    for (int j = 0; j < 4; ++j) { ssum[tr][sub * 4 + j] = s[j]; ssq[tr][sub * 4 + j] = q[j]; }
    __syncthreads();
    if (threadIdx.x < 64) {
        const int c = threadIdx.x;
        float S = 0.f, Q = 0.f;
        #pragma unroll
        for (int r = 0; r < 16; ++r) { S += ssum[r][c]; Q += ssq[r][c]; }
        const float var = (Q - S * S * (1.f / 4096.f)) * (1.f / 4095.f);
        const int cglob = cg * 64 + c;
        sout[b * CDIM + cglob] = wgt[cglob] / (sqrtf(var) + eps);
    }
}

// ---------------- h = x * s1, BCHW f32 -> BHWC bf16 ----------------
__global__ __launch_bounds__(256) void make_h(
    const float* __restrict__ x, const float* __restrict__ s1,
    unsigned short* __restrict__ h)
{
    const int hw0 = blockIdx.x * 64, c0 = blockIdx.y * 64, b = blockIdx.z;
    __shared__ float t[64][65];
    #pragma unroll
    for (int s = 0; s < 16; ++s) {
        int flat = threadIdx.x + 256 * s;
        int ci = flat >> 6, hj = flat & 63;
        t[ci][hj] = x[(long)(b * CDIM + c0 + ci) * HWD + hw0 + hj];
    }
    __syncthreads();
    #pragma unroll
    for (int s = 0; s < 16; ++s) {
        int flat = threadIdx.x + 256 * s;
        int hi = flat >> 6, cj = flat & 63;
        float v = t[cj][hi] * s1[b * CDIM + c0 + cj];
        h[(long)(b * HWD + hw0 + hi) * CDIM + c0 + cj] = f2bf(v);
    }
}

// ---------------- GEMM 256x128 tile, BK_sub=32, 2-slot dbuf, 2 blocks/CU (best: R12) ----------------
// out[M][N] = A[M][K] * BT[N][K]^T (+bias)(+gelu), bf16 in/out.
// 512 threads = 8 waves (4m x 2n), per-wave 64x64 (acc 64 AGPR) -> 2 independent
// blocks/CU (cross-block phase overlap). LDS 48KB: A [2][256][32] elems, B [2][128][32]
// at +16384. Granule swizzle: 16B granule (row,pos) holds k-chunk pos ^ ((row>>1)&3).
template<int GELU>
__global__ __launch_bounds__(512, 4) void gemm256(
    const unsigned short* __restrict__ A, const unsigned short* __restrict__ BT,
    const float* __restrict__ bias, unsigned short* __restrict__ out,
    int M, int N, int K)
{
    extern __shared__ unsigned short smem[];
    const int tid = threadIdx.x;
    const int lane = tid & 63, w = tid >> 6;
    const int wm = w >> 1, wn = w & 1;            // 4 x 2 waves
    const int lr = lane & 15, g = lane >> 4;

    // T1: XCD-contiguous logical id, n fastest (A-panel shared in XCD L2)
    const int nwg = gridDim.x;
    const int logical = (blockIdx.x & 7) * (nwg >> 3) + (blockIdx.x >> 3);
    const int gnx = N >> 7;
    const int n0 = (logical % gnx) << 7;
    const int m0 = (logical / gnx) << 8;

    const int ka = (((tid & 3) ^ ((tid >> 3) & 3)) << 3);
    const unsigned short* aS0 = A + (long)(m0 + (tid >> 2)) * K + ka;
    const unsigned short* aS1 = A + (long)(m0 + 128 + (tid >> 2)) * K + ka;
    const unsigned short* bS = BT + (long)(n0 + (tid >> 2)) * K + ka;
    unsigned short* dA0 = smem + (tid & ~63) * 8;
    unsigned short* dA1 = dA0 + 4096;
    unsigned short* dB  = smem + 16384 + (tid & ~63) * 8;

#define GSTAGE(S) do { \
        gload_lds16(aS0, dA0 + (S) * 8192); \
        gload_lds16(aS1, dA1 + (S) * 8192); \
        gload_lds16(bS,  dB  + (S) * 4096); \
        aS0 += 32; aS1 += 32; bS += 32; } while (0)

    const int nsub = K >> 5;
    const int koff = ((g ^ ((lr >> 1) & 3)) << 3);
    const unsigned short* baseA = smem + (wm * 64 + lr) * 32 + koff;
    const unsigned short* baseB = smem + 16384 + (wn * 64 + lr) * 32 + koff;

    f32x4 acc[4][4] = {};

    GSTAGE(0); GSTAGE(1);

#define SUBTILE(U, STG, WAITN) do { \
        asm volatile("s_waitcnt vmcnt(" #WAITN ")" ::: "memory"); \
        __builtin_amdgcn_s_barrier(); \
        short8 bf[4], af[4]; \
        _Pragma("unroll") \
        for (int ni = 0; ni < 4; ++ni) bf[ni] = *(const short8*)(baseB + (U) * 4096 + ni * 512); \
        _Pragma("unroll") \
        for (int mi = 0; mi < 4; ++mi) af[mi] = *(const short8*)(baseA + (U) * 8192 + mi * 512); \
        asm volatile("s_waitcnt lgkmcnt(0)" ::: "memory"); \
        __builtin_amdgcn_s_barrier(); \
        __builtin_amdgcn_sched_barrier(0); \
        STG; \
        __builtin_amdgcn_s_setprio(1); \
        _Pragma("unroll") \
        for (int mi = 0; mi < 4; ++mi) \
            _Pragma("unroll") \
            for (int ni = 0; ni < 4; ++ni) \
                acc[mi][ni] = __builtin_amdgcn_mfma_f32_16x16x32_bf16(af[mi], bf[ni], acc[mi][ni], 0, 0, 0); \
        __builtin_amdgcn_s_setprio(0); \
        __builtin_amdgcn_sched_barrier(0); } while (0)

    for (int j2 = 0; j2 + 2 < nsub; j2 += 2) {
        SUBTILE(0, GSTAGE(0), 3);
        SUBTILE(1, GSTAGE(1), 3);
    }
    SUBTILE(0, , 3);
    SUBTILE(1, , 0);
#undef SUBTILE
#undef GSTAGE

    #pragma unroll
    for (int mi = 0; mi < 4; ++mi) {
        #pragma unroll
        for (int ni = 0; ni < 4; ++ni) {
            const int gcol = n0 + wn * 64 + ni * 16 + lr;
            const float bv = bias[gcol];
            #pragma unroll
            for (int r = 0; r < 4; ++r) {
                const int grow = m0 + wm * 64 + mi * 16 + g * 4 + r;
                float v = acc[mi][ni][r] + bv;
                if (GELU) v = 0.5f * v * (1.f + erff(v * 0.70710678118f));
                out[(long)grow * N + gcol] = f2bf(v);
            }
        }
    }
}

// ---------------- per-head q/k LayerNorm (ddof=0, eps 1e-5) in place ----------------
__global__ __launch_bounds__(256) void qk_layernorm(
    unsigned short* __restrict__ qkv,
    const float* __restrict__ qw, const float* __restrict__ qb,
    const float* __restrict__ kw, const float* __restrict__ kb)
{
    const int pairIdx = blockIdx.x * 16 + (threadIdx.x >> 4);
    const int token = pairIdx / HEADS, he = pairIdx % HEADS;
    const int c4 = (threadIdx.x & 15) * 4;
    const long base = (long)token * C3 + he * 192;
    #pragma unroll
    for (int which = 0; which < 2; ++which) {
        const long off = base + which * 64 + c4;
        u16x4 v = *(u16x4*)&qkv[off];
        float f[4];
        #pragma unroll
        for (int j = 0; j < 4; ++j) f[j] = bf2f(v[j]);
        float s = f[0] + f[1] + f[2] + f[3];
        float q = f[0] * f[0] + f[1] * f[1] + f[2] * f[2] + f[3] * f[3];
        #pragma unroll
        for (int m = 1; m < 16; m <<= 1) { s += __shfl_xor(s, m); q += __shfl_xor(q, m); }
        const float mean = s * (1.f / 64.f);
        const float var = q * (1.f / 64.f) - mean * mean;
        const float rstd = rsqrtf(var + 1e-5f);
        const float* W = which ? kw : qw;
        const float* Bv = which ? kb : qb;
        u16x4 o;
        #pragma unroll
        for (int j = 0; j < 4; ++j)
            o[j] = f2bf((f[j] - mean) * rstd * W[c4 + j] + Bv[c4 + j]);
        *(u16x4*)&qkv[off] = o;
    }
}

// ---------------- axial attention: one wave per (b,head,line); AXIS 0=row(attend W), 1=col(attend H) ----------------
template<int AXIS>
__global__ __launch_bounds__(128) void attn_axial(
    const unsigned short* __restrict__ qkv, unsigned short* __restrict__ a)
{
    __shared__ unsigned short lds[2][2][64 * 72];
    const int tid = threadIdx.x;
    const int lane = tid & 63, w = tid >> 6;
    const int lineG = blockIdx.x * 2 + w;
    const int b = lineG / 768;
    const int rem = lineG - b * 768;
    const int he = rem >> 6, line = rem & 63;
    const int ts = (AXIS == 0) ? 1 : 64;
    const long token0 = (long)b * HWD + (AXIS == 0 ? line * 64 : line);
    const long qbase = token0 * C3 + he * 192;
    unsigned short* VT = &lds[w][0][0];
    unsigned short* P  = &lds[w][1][0];
    const int lr = lane & 15, g = lane >> 4;

    // stage V transposed: VT[d][key], rows padded to 72
    {
        const int keyr = lane >> 3, d8 = (lane & 7) << 3;
        #pragma unroll
        for (int it = 0; it < 8; ++it) {
            const int key = it * 8 + keyr;
            u16x8 v = *(const u16x8*)&qkv[qbase + (long)key * ts * C3 + 128 + d8];
            #pragma unroll
            for (int j = 0; j < 8; ++j) VT[(d8 + j) * 72 + key] = v[j];
        }
    }

    // Q,K fragments straight from global
    short8 qf[4][2], kf[4][2];
    #pragma unroll
    for (int i = 0; i < 4; ++i)
        #pragma unroll
        for (int kk = 0; kk < 2; ++kk) {
            const long rb = qbase + (long)(i * 16 + lr) * ts * C3 + kk * 32 + g * 8;
            qf[i][kk] = *(const short8*)&qkv[rb];
            kf[i][kk] = *(const short8*)&qkv[rb + 64];
        }

    f32x4 acc[4][4] = {};
    #pragma unroll
    for (int mi = 0; mi < 4; ++mi)
        #pragma unroll
        for (int ni = 0; ni < 4; ++ni) {
            acc[mi][ni] = __builtin_amdgcn_mfma_f32_16x16x32_bf16(qf[mi][0], kf[ni][0], acc[mi][ni], 0, 0, 0);
            acc[mi][ni] = __builtin_amdgcn_mfma_f32_16x16x32_bf16(qf[mi][1], kf[ni][1], acc[mi][ni], 0, 0, 0);
        }

    // softmax per row (scale 1/8); D layout: row = mi*16+4g+r, col = ni*16+lr
    #pragma unroll
    for (int mi = 0; mi < 4; ++mi)
        #pragma unroll
        for (int r = 0; r < 4; ++r) {
            float mx = -1e30f;
            #pragma unroll
            for (int ni = 0; ni < 4; ++ni) {
                float v = acc[mi][ni][r] * 0.125f; acc[mi][ni][r] = v; mx = fmaxf(mx, v);
            }
            #pragma unroll
            for (int m = 1; m < 16; m <<= 1) mx = fmaxf(mx, __shfl_xor(mx, m));
            float s = 0.f;
            #pragma unroll
            for (int ni = 0; ni < 4; ++ni) {
                float e = __expf(acc[mi][ni][r] - mx); acc[mi][ni][r] = e; s += e;
            }
            #pragma unroll
            for (int m = 1; m < 16; m <<= 1) s += __shfl_xor(s, m);
            const float inv = 1.f / s;
            const int row = mi * 16 + 4 * g + r;
            #pragma unroll
            for (int ni = 0; ni < 4; ++ni)
                P[row * 72 + ni * 16 + lr] = f2bf(acc[mi][ni][r] * inv);
        }
    __syncthreads();

    // PV
    short8 pa[4][2], vb[4][2];
    #pragma unroll
    for (int i = 0; i < 4; ++i)
        #pragma unroll
        for (int kk = 0; kk < 2; ++kk) {
            pa[i][kk] = *(const short8*)&P[(i * 16 + lr) * 72 + kk * 32 + g * 8];
            vb[i][kk] = *(const short8*)&VT[(i * 16 + lr) * 72 + kk * 32 + g * 8];
        }
    f32x4 o2[4][4] = {};
    #pragma unroll
    for (int mi = 0; mi < 4; ++mi)
        #pragma unroll
        for (int ni = 0; ni < 4; ++ni) {
            o2[mi][ni] = __builtin_amdgcn_mfma_f32_16x16x32_bf16(pa[mi][0], vb[ni][0], o2[mi][ni], 0, 0, 0);
            o2[mi][ni] = __builtin_amdgcn_mfma_f32_16x16x32_bf16(pa[mi][1], vb[ni][1], o2[mi][ni], 0, 0, 0);
        }

    // write 0.5*result; col pass accumulates onto row pass
    #pragma unroll
    for (int mi = 0; mi < 4; ++mi)
        #pragma unroll
        for (int r = 0; r < 4; ++r) {
            const int q = mi * 16 + 4 * g + r;
            const long tok = token0 + (long)q * ts;
            #pragma unroll
            for (int ni = 0; ni < 4; ++ni) {
                const int d = ni * 16 + lr;
                const long addr = tok * CDIM + he * 64 + d;
                const float v = o2[mi][ni][r] * 0.5f;
                if (AXIS == 0) a[addr] = f2bf(v);
                else           a[addr] = f2bf(bf2f(a[addr]) + v);
            }
        }
}

// ---------------- a *= s2[b][c] in place (bf16 BHWC) ----------------
__global__ __launch_bounds__(256) void scale_inplace(
    unsigned short* __restrict__ a, const float* __restrict__ s2)
{
    const long i = ((long)blockIdx.x * 256 + threadIdx.x) * 4;
    const int c = (int)(i % CDIM);
    const int b = (int)(i / ((long)CDIM * HWD));
    u16x4 v = *(u16x4*)&a[i];
    u16x4 o;
    #pragma unroll
    for (int j = 0; j < 4; ++j) o[j] = f2bf(bf2f(v[j]) * s2[b * CDIM + c + j]);
    *(u16x4*)&a[i] = o;
}

// ---------------- x1 = x + gamma_att*o : write f32 BCHW (d_out) and bf16 BHWC ----------------
__global__ __launch_bounds__(256) void x1_combine(
    const unsigned short* __restrict__ o, const float* __restrict__ x,
    const float* __restrict__ gamma, float* __restrict__ dout,
    unsigned short* __restrict__ x1b)
{
    const int hw0 = blockIdx.x * 64, c0 = blockIdx.y * 64, b = blockIdx.z;
    __shared__ float t[64][65];
    #pragma unroll
    for (int s = 0; s < 16; ++s) {
        int flat = threadIdx.x + 256 * s;
        int i = flat >> 6, j = flat & 63;
        t[i][j] = bf2f(o[(long)(b * HWD + hw0 + i) * CDIM + c0 + j]);
    }
    __syncthreads();
    #pragma unroll
    for (int s = 0; s < 16; ++s) {
        int flat = threadIdx.x + 256 * s;
        int j = flat >> 6, i = flat & 63;
        const long xi = (long)(b * CDIM + c0 + j) * HWD + hw0 + i;
        float v = x[xi] + gamma[c0 + j] * t[i][j];
        dout[xi] = v;
        t[i][j] = v;
    }
    __syncthreads();
    #pragma unroll
    for (int s = 0; s < 16; ++s) {
        int flat = threadIdx.x + 256 * s;
        int i = flat >> 6, j = flat & 63;
        x1b[(long)(b * HWD + hw0 + i) * CDIM + c0 + j] = f2bf(t[i][j]);
    }
}

// ---------------- out += gamma_mlp * s3 * m (m bf16 BHWC -> f32 BCHW RMW) ----------------
__global__ __launch_bounds__(256) void final_combine(
    const unsigned short* __restrict__ m, const float* __restrict__ gm,
    const float* __restrict__ s3, float* __restrict__ dout)
{
    const int hw0 = blockIdx.x * 64, c0 = blockIdx.y * 64, b = blockIdx.z;
    __shared__ float t[64][65];
    #pragma unroll
    for (int s = 0; s < 16; ++s) {
        int flat = threadIdx.x + 256 * s;
        int i = flat >> 6, j = flat & 63;
        t[i][j] = bf2f(m[(long)(b * HWD + hw0 + i) * CDIM + c0 + j]);
    }
    __syncthreads();
    #pragma unroll
    for (int s = 0; s < 16; ++s) {
        int flat = threadIdx.x + 256 * s;
        int j = flat >> 6, i = flat & 63;
        const long xi = (long)(b * CDIM + c0 + j) * HWD + hw0 + i;
        dout[xi] = dout[xi] + gm[c0 + j] * s3[b * CDIM + c0 + j] * t[i][j];
    }
}

extern "C" void kernel_launch(void* const* d_in, const int* in_sizes, int n_in,
                              void* d_out, int out_size, void* d_ws, size_t ws_size,
                              hipStream_t stream) {
    const float* x      = (const float*)d_in[0];
    const float* n1w    = (const float*)d_in[2];
    const float* n2w    = (const float*)d_in[3];
    const float* mlw    = (const float*)d_in[4];
    const float* Win    = (const float*)d_in[5];
    const float* bin    = (const float*)d_in[6];
    const float* Wout   = (const float*)d_in[7];
    const float* bout   = (const float*)d_in[8];
    const float* qn_w   = (const float*)d_in[9];
    const float* qn_b   = (const float*)d_in[10];
    const float* kn_w   = (const float*)d_in[11];
    const float* kn_b   = (const float*)d_in[12];
    const float* gatt   = (const float*)d_in[13];
    const float* gmlp   = (const float*)d_in[14];
    const float* W1     = (const float*)d_in[15];
    const float* b1     = (const float*)d_in[16];
    const float* W2     = (const float*)d_in[17];
    const float* b2     = (const float*)d_in[18];
    float* dout = (float*)d_out;
    char* ws = (char*)d_ws;

    unsigned short* wQ  = (unsigned short*)(ws);                  // Win  bf16 [2304][768]
    unsigned short* wO  = (unsigned short*)(ws + (4L << 20));     // Wout bf16 [768][768]
    unsigned short* w1t = (unsigned short*)(ws + (6L << 20));     // W1^T bf16 [3072][768]
    unsigned short* w2t = (unsigned short*)(ws + (11L << 20));    // W2^T bf16 [768][3072]
    float* s1 = (float*)(ws + (16L << 20));
    float* s2 = s1 + 6144;
    float* s3 = s2 + 6144;
    unsigned short* bufH = (unsigned short*)(ws + (17L << 20));   // 48MB: h -> o -> m
    unsigned short* bufQ = (unsigned short*)(ws + (65L << 20));   // 144MB: qkv -> hidden
    unsigned short* bufA = (unsigned short*)(ws + (209L << 20));  // 48MB: a -> x1 (bhwc)

    // weight prep
    convert_f32_bf16<<<1728, 256, 0, stream>>>(Win, wQ, C3 * CDIM);
    convert_f32_bf16<<<576, 256, 0, stream>>>(Wout, wO, CDIM * CDIM);
    transpose_w<<<dim3(C4 / 64, CDIM / 64), 256, 0, stream>>>(W1, w1t, CDIM, C4);
    transpose_w<<<dim3(CDIM / 64, C4 / 64), 256, 0, stream>>>(W2, w2t, C4, CDIM);

    // norm1 + h
    stats_spatial_f32<<<BDIM * CDIM, 256, 0, stream>>>(x, n1w, s1, 1e-6f);
    make_h<<<dim3(64, 12, 8), 256, 0, stream>>>(x, s1, bufH);

    // qkv = h @ Win^T + bin   (grid 128*18 = 2304 blocks)
    gemm256<0><<<(TOKS / 256) * (C3 / 128), 512, 49152, stream>>>(bufH, wQ, bin, bufQ, TOKS, C3, CDIM);
    qk_layernorm<<<TOKS * HEADS / 16, 256, 0, stream>>>(bufQ, qn_w, qn_b, kn_w, kn_b);

    // axial attention, a = 0.5*(xx + xy)
    attn_axial<0><<<BDIM * HEADS * 64 / 2, 128, 0, stream>>>(bufQ, bufA);
    attn_axial<1><<<BDIM * HEADS * 64 / 2, 128, 0, stream>>>(bufQ, bufA);

    // norm2 + Wout + residual   (grid 128*6 = 768)
    stats_spatial_bf16<<<BDIM * 12, 256, 0, stream>>>(bufA, n2w, s2, 1e-6f);
    scale_inplace<<<TOKS * CDIM / 1024, 256, 0, stream>>>(bufA, s2);
    gemm256<0><<<(TOKS / 256) * (CDIM / 128), 512, 49152, stream>>>(bufA, wO, bout, bufH, TOKS, CDIM, CDIM);
    x1_combine<<<dim3(64, 12, 8), 256, 0, stream>>>(bufH, x, gatt, dout, bufA);

    // MLP in 2 token chunks (hidden reuses bufQ); grids 64*24=1536, 64*6=384
    for (int ch = 0; ch < 2; ++ch) {
        const unsigned short* x1c = bufA + (long)ch * 16384 * CDIM;
        unsigned short* mc = bufH + (long)ch * 16384 * CDIM;
        gemm256<1><<<(16384 / 256) * (C4 / 128), 512, 49152, stream>>>(x1c, w1t, b1, bufQ, 16384, C4, CDIM);
        gemm256<0><<<(16384 / 256) * (CDIM / 128), 512, 49152, stream>>>(bufQ, w2t, b2, mc, 16384, CDIM, C4);
    }

    // mlp norm + final residual
    stats_spatial_bf16<<<BDIM * 12, 256, 0, stream>>>(bufH, mlw, s3, 1e-6f);
    final_combine<<<dim3(64, 12, 8), 256, 0, stream>>>(bufH, gmlp, s3, dout);
}